// Round 3
// baseline (107.125 us; speedup 1.0000x reference)
//
#include <hip/hip_runtime.h>
#include <math.h>

// Segment max: out[seg][d] = max over rows r with batch[r]==seg of x[r][d].
// batch sorted int32, B segments, D=128 floats/row = 32 float4.
//
// Kernel A: coalesced boundary scan of batch (int4 reads, neighbor compare)
//           -> bounds[0..B] in workspace. ~1-2 us (vs ~8 us of binary search).
// Kernel B: one block per segment; 8 row-groups of 32 lanes, each group owns a
//           contiguous chunk of rows; unroll-4 float4 loads with imm offsets
//           (0/512/1024/1536 B); LDS tree reduce; float4 store.

__global__ __launch_bounds__(256) void bounds_scan_kernel(
    const int* __restrict__ batch, int* __restrict__ bounds, int N, int B) {
    int g  = blockIdx.x * 256 + threadIdx.x;   // 4-element chunk index
    int i0 = g * 4;
    if (i0 >= N) return;

    int v[5];
    if (i0 + 3 < N) {
        int4 c = reinterpret_cast<const int4*>(batch)[g];
        v[0] = c.x; v[1] = c.y; v[2] = c.z; v[3] = c.w;
    } else {
        for (int j = 0; j < 4; ++j) v[j] = (i0 + j < N) ? batch[i0 + j] : 0;
    }
    v[4] = (i0 + 4 < N) ? batch[i0 + 4] : 0;

    if (g == 0) {
        for (int s = 0; s <= v[0]; ++s) bounds[s] = 0;   // leading (empty) segs
    }
    #pragma unroll
    for (int j = 0; j < 4; ++j) {
        int i = i0 + j;
        if (i + 1 < N) {
            if (v[j] != v[j + 1])
                for (int s = v[j] + 1; s <= v[j + 1]; ++s) bounds[s] = i + 1;
        } else {
            for (int s = v[j] + 1; s <= B; ++s) bounds[s] = N;  // trailing
        }
    }
}

__device__ __forceinline__ float4 max4(float4 a, float4 b) {
    a.x = fmaxf(a.x, b.x);
    a.y = fmaxf(a.y, b.y);
    a.z = fmaxf(a.z, b.z);
    a.w = fmaxf(a.w, b.w);
    return a;
}

__global__ __launch_bounds__(256, 8) void seg_max_kernel(
    const float* __restrict__ x, const int* __restrict__ bounds,
    float* __restrict__ out) {
    const int seg   = blockIdx.x;
    const int start = bounds[seg];       // wave-uniform broadcast loads
    const int end   = bounds[seg + 1];

    const int tid  = threadIdx.x;
    const int col4 = tid & 31;   // float4 index within the 512B row
    const int rg   = tid >> 5;   // row group 0..7

    // Contiguous chunk of rows per group (balanced split of len over 8).
    const int len = end - start;
    const int cb  = len >> 3;
    const int rem = len & 7;
    const int gs  = start + rg * cb + (rg < rem ? rg : rem);
    const int ge  = gs + cb + (rg < rem ? 1 : 0);

    const float4* __restrict__ x4 = reinterpret_cast<const float4*>(x);
    const float4 ninf = make_float4(-INFINITY, -INFINITY, -INFINITY, -INFINITY);
    float4 m0 = ninf, m1 = ninf, m2 = ninf, m3 = ninf;

    const float4* __restrict__ p = x4 + (size_t)gs * 32 + col4;
    int r = gs;
    // Unroll-4: rows r..r+3 -> imm offsets 0/512/1024/1536 B, 4 loads in flight.
    for (; r + 3 < ge; r += 4, p += 128) {
        float4 v0 = p[0];
        float4 v1 = p[32];
        float4 v2 = p[64];
        float4 v3 = p[96];
        m0 = max4(m0, v0);
        m1 = max4(m1, v1);
        m2 = max4(m2, v2);
        m3 = max4(m3, v3);
    }
    for (; r < ge; ++r, p += 32) m0 = max4(m0, p[0]);
    float4 m = max4(max4(m0, m1), max4(m2, m3));

    // Reduce the 8 row groups (tid = rg*32 + col4; stride-32 pairs share col4).
    __shared__ float4 smem[256];
    smem[tid] = m;
    __syncthreads();
    #pragma unroll
    for (int step = 128; step >= 32; step >>= 1) {
        if (tid < step) {
            smem[tid] = max4(smem[tid], smem[tid + step]);
        }
        __syncthreads();
    }
    if (tid < 32) {
        reinterpret_cast<float4*>(out)[(size_t)seg * 32 + tid] = smem[tid];
    }
}

extern "C" void kernel_launch(void* const* d_in, const int* in_sizes, int n_in,
                              void* d_out, int out_size, void* d_ws, size_t ws_size,
                              hipStream_t stream) {
    const float* x      = (const float*)d_in[0];
    const int*   batch  = (const int*)d_in[1];
    float*       out    = (float*)d_out;
    int*         bounds = (int*)d_ws;    // (B+1) ints

    const int D = 128;
    const int N = in_sizes[0] / D;
    const int B = out_size / D;          // 2048 segments

    const int chunks = (N + 3) / 4;
    bounds_scan_kernel<<<(chunks + 255) / 256, 256, 0, stream>>>(batch, bounds, N, B);
    seg_max_kernel<<<B, 256, 0, stream>>>(x, bounds, out);
}

// Round 4
// 99.883 us; speedup vs baseline: 1.0725x; 1.0725x over previous
//
#include <hip/hip_runtime.h>
#include <math.h>

// Segment max, row-range decomposition:
//   out[seg][d] = max over rows r with batch[r]==seg of x[r][d]
// batch sorted int32, D=128 floats/row = 32 float4.
//
// Kernel A: init out to -inf (1 MiB; identity of max, covers empty segments
//           and the cross-block atomic fallback).
// Kernel B: one block per R-row range. Block reads batch[r0]/batch[r1-1] to
//           find the segments it touches (no bounds array, no prefix kernel).
//           For each segment run in range: nontemporal float4 streaming max
//           (8 row-groups x 32 lanes, contiguous chunks, unroll-4), LDS tree
//           reduce, then direct store if the run is interior, atomic-max if
//           the segment spans a block edge. On this input R == segment size,
//           so every block is exactly one contained segment -> direct store.

typedef float f32x4 __attribute__((ext_vector_type(4)));

__device__ __forceinline__ f32x4 max4(f32x4 a, f32x4 b) {
    a.x = fmaxf(a.x, b.x);
    a.y = fmaxf(a.y, b.y);
    a.z = fmaxf(a.z, b.z);
    a.w = fmaxf(a.w, b.w);
    return a;
}

// Order-independent float atomic max (memory init'd to -inf):
// positive floats order like ints; negative floats reverse-order like uints.
__device__ __forceinline__ void atomic_max_f32(float* addr, float v) {
    if (v >= 0.0f) atomicMax((int*)addr, __float_as_int(v));
    else           atomicMin((unsigned int*)addr, __float_as_uint(v));
}

__global__ __launch_bounds__(256) void init_out_kernel(float4* out4, int n4) {
    int i = blockIdx.x * 256 + threadIdx.x;
    if (i < n4)
        out4[i] = make_float4(-INFINITY, -INFINITY, -INFINITY, -INFINITY);
}

__global__ __launch_bounds__(256, 4) void seg_max_rows_kernel(
    const float* __restrict__ x, const int* __restrict__ batch,
    float* __restrict__ out, int N, int R) {
    const int r0 = blockIdx.x * R;
    if (r0 >= N) return;
    const int r1 = min(r0 + R, N);

    const int tid  = threadIdx.x;
    const int col4 = tid & 31;   // float4 index within the 512B row
    const int rg   = tid >> 5;   // row group 0..7

    const int sFirst = batch[r0];
    const int sLast  = batch[r1 - 1];

    const f32x4* __restrict__ x4 = reinterpret_cast<const f32x4*>(x);
    __shared__ f32x4 smem[256];

    // Block-uniform loop over the segments present in [r0, r1).
    for (int s = sFirst; s <= sLast; ++s) {
        int a = r0, b = r1;
        if (s > sFirst) {            // lower_bound(s) in [r0, r1)
            int lo = r0, hi = r1;
            while (lo < hi) {
                int mid = (lo + hi) >> 1;
                if (batch[mid] < s) lo = mid + 1; else hi = mid;
            }
            a = lo;
        }
        if (s < sLast) {             // upper_bound(s) in [a, r1)
            int lo = a, hi = r1;
            while (lo < hi) {
                int mid = (lo + hi) >> 1;
                if (batch[mid] <= s) lo = mid + 1; else hi = mid;
            }
            b = lo;
        }
        if (a < b) {
            // Contiguous chunk of rows per row-group (balanced split over 8).
            const int len = b - a;
            const int cb  = len >> 3;
            const int rem = len & 7;
            const int gs  = a + rg * cb + (rg < rem ? rg : rem);
            const int ge  = gs + cb + (rg < rem ? 1 : 0);

            f32x4 m0 = {-INFINITY, -INFINITY, -INFINITY, -INFINITY};
            f32x4 m1 = m0, m2 = m0, m3 = m0;

            // Half-wave reads one contiguous 512B row; nt = bypass L2 retention.
            const f32x4* p = x4 + (size_t)gs * 32 + col4;
            int r = gs;
            for (; r + 3 < ge; r += 4, p += 128) {
                f32x4 v0 = __builtin_nontemporal_load(p);
                f32x4 v1 = __builtin_nontemporal_load(p + 32);
                f32x4 v2 = __builtin_nontemporal_load(p + 64);
                f32x4 v3 = __builtin_nontemporal_load(p + 96);
                m0 = max4(m0, v0);
                m1 = max4(m1, v1);
                m2 = max4(m2, v2);
                m3 = max4(m3, v3);
            }
            for (; r < ge; ++r, p += 32) m0 = max4(m0, __builtin_nontemporal_load(p));
            f32x4 m = max4(max4(m0, m1), max4(m2, m3));

            // Reduce 8 row groups (tid = rg*32 + col4; stride-32 pairs share col4).
            smem[tid] = m;
            __syncthreads();
            #pragma unroll
            for (int step = 128; step >= 32; step >>= 1) {
                if (tid < step) smem[tid] = max4(smem[tid], smem[tid + step]);
                __syncthreads();
            }

            if (tid < 32) {
                f32x4 v = smem[tid];
                const bool edge = (a == r0 && r0 > 0 && batch[r0 - 1] == s) ||
                                  (b == r1 && r1 < N && batch[r1] == s);
                float* o = out + (size_t)s * 128 + col4 * 4;
                if (edge) {   // segment spans a block boundary (never on this input)
                    atomic_max_f32(o + 0, v.x);
                    atomic_max_f32(o + 1, v.y);
                    atomic_max_f32(o + 2, v.z);
                    atomic_max_f32(o + 3, v.w);
                } else {
                    *reinterpret_cast<float4*>(o) = make_float4(v.x, v.y, v.z, v.w);
                }
            }
        }
        __syncthreads();   // smem reused next segment iteration
    }
}

extern "C" void kernel_launch(void* const* d_in, const int* in_sizes, int n_in,
                              void* d_out, int out_size, void* d_ws, size_t ws_size,
                              hipStream_t stream) {
    const float* x     = (const float*)d_in[0];
    const int*   batch = (const int*)d_in[1];
    float*       out   = (float*)d_out;

    const int D = 128;
    const int N = in_sizes[0] / D;

    const int n4 = out_size / 4;
    init_out_kernel<<<(n4 + 255) / 256, 256, 0, stream>>>((float4*)d_out, n4);

    // ~2048 blocks; R == 512 rows per block for this input (N = 2048 * 512).
    const int R    = (N + 2047) / 2048;
    const int grid = (N + R - 1) / R;
    seg_max_rows_kernel<<<grid, 256, 0, stream>>>(x, batch, out, N, R);
}